// Round 12
// baseline (218.835 us; speedup 1.0000x reference)
//
#include <hip/hip_runtime.h>
#include <hip/hip_bf16.h>
#include <cmath>

#define N_NODES 50000
#define N_EDGES 800000
#define D_IN 256
#define D_HID 128
#define D_ENC 64
#define NBUKS 98         // scan buckets of 512 nodes
#define BCAPS 16384      // u16 srcs slots per bucket (expected 8192, 90-sigma margin)
#define NPREPB 9         // prep blocks (4608 threads cover swizzle+fold)
#define NDEGB 196        // ceil(N_EDGES/4096) degree/scatter blocks
#define NGEMB 782        // ceil(50048/64) GEMM tile-blocks total
#define NGEMB_A 391      // half A (rows 0..25023)
#define NGEMB_B 391      // half B (rows 25024..50047)
#define DYN_LDS 33792    // GEMM As: 64*(D_IN+8)*2

typedef short short8 __attribute__((ext_vector_type(8)));
typedef float floatx4 __attribute__((ext_vector_type(4)));
typedef float floatx8 __attribute__((ext_vector_type(8)));
typedef unsigned short ushort8v __attribute__((ext_vector_type(8)));

static __device__ __forceinline__ unsigned short f2bf(float f) {
    unsigned int u = __float_as_uint(f);
    unsigned int r = (u + 0x7FFFu + ((u >> 16) & 1u)) >> 16;   // RNE
    return (unsigned short)r;
}
static __device__ __forceinline__ float bf2f(unsigned short u) {
    return __uint_as_float(((unsigned int)u) << 16);
}
static __device__ __forceinline__ floatx8 bf2f8(ushort8v u) {
    floatx8 f;
#pragma unroll
    for (int j = 0; j < 8; ++j) f[j] = bf2f(u[j]);
    return f;
}

// ---------------- W pre-swizzle into B-fragment layout (bf16) ----------------
static __device__ __forceinline__ void wswz(const float* __restrict__ W,
                                            unsigned short* __restrict__ Wsw,
                                            int t, int K, int N) {
    int KS = K / 32;
    int lane = t & 63;
    int ks   = (t >> 6) % KS;
    int ct   = (t >> 6) / KS;
    int m = lane & 15, quad = lane >> 4;
    int kbase = ks * 32 + quad * 8;
    int col   = ct * 16 + m;
#pragma unroll
    for (int j = 0; j < 8; ++j)
        Wsw[t * 8 + j] = f2bf(W[(size_t)(kbase + j) * N + col]);
}

// ---------------- D1: prep (9 blocks) || in-degree count (196 blocks) ----------------
// rowcnt must be pre-zeroed (memset in stream before this dispatch).
__global__ __launch_bounds__(512) void pd_k(const float* __restrict__ W1,
                                            const float* __restrict__ W2,
                                            const float* __restrict__ b2,
                                            const float* __restrict__ Wfc,
                                            unsigned short* __restrict__ Wsw1,
                                            float* __restrict__ w2fc,
                                            float* __restrict__ b2fc,
                                            const int* __restrict__ cols,
                                            int* __restrict__ rowcnt) {
    int tid = threadIdx.x;
    if (blockIdx.x < NPREPB) {
        int t = blockIdx.x * 512 + tid;           // 0..4607
        if (t < 4096) wswz(W1, Wsw1, t, D_IN, D_HID);
        else if (t < 4224) {                      // w2fc[c] = sum_j W2[c][j]*Wfc[j]
            int c = t - 4096;
            float s = 0.0f;
#pragma unroll 8
            for (int j = 0; j < D_ENC; ++j) s += W2[c * D_ENC + j] * Wfc[j];
            w2fc[c] = s;
        } else if (t == 4224) {                   // b2fc = b2 @ Wfc
            float s = 0.0f;
            for (int j = 0; j < D_ENC; ++j) s += b2[j] * Wfc[j];
            b2fc[0] = s;
        }
    } else {
        int e0 = (blockIdx.x - NPREPB) * 4096;
#pragma unroll
        for (int j = 0; j < 8; ++j) {
            int e = e0 + j * 512 + tid;
            if (e < N_EDGES) atomicAdd(&rowcnt[cols[e]], 1);
        }
    }
}

// ---------------- device: one 64-row MFMA GEMM tile (512 thr) ----------------
// H[r,:] = bf16(X[r,:] @ W1)   (dinv weighting applied in the gather)
static __device__ void gemm_path(char* dynsm, int row0,
                                 const floatx4* X4, const unsigned short* Wsw,
                                 unsigned short* H) {
    constexpr int KP = D_IN + 8;   // 264
    unsigned short* As = (unsigned short*)dynsm;    // 64*KP u16 (33 KB)
    int tid = threadIdx.x;
    for (int idx = tid; idx < 64 * 64; idx += 512) {
        int r = idx >> 6, c4 = idx & 63;
        int gr = row0 + r;
        floatx4 v = (gr < N_NODES) ? X4[(size_t)gr * 64 + c4] : (floatx4){0, 0, 0, 0};
        __hip_bfloat162 p0 = __float22bfloat162_rn(float2{v[0], v[1]});   // packed RNE cvt
        __hip_bfloat162 p1 = __float22bfloat162_rn(float2{v[2], v[3]});
        uint2 u; u.x = *(unsigned int*)&p0; u.y = *(unsigned int*)&p1;
        *(uint2*)&As[r * KP + c4 * 4] = u;
    }
    __syncthreads();

    int w    = tid >> 6;
    int lane = tid & 63;
    int m    = lane & 15;
    int quad = lane >> 4;
    int rsub = w & 3;
    int cth  = w >> 2;              // 0/1: which 4 col-tiles

    floatx4 acc[4];
#pragma unroll
    for (int ct = 0; ct < 4; ++ct)
#pragma unroll
        for (int i = 0; i < 4; ++i) acc[ct][i] = 0.0f;

#pragma unroll
    for (int ks = 0; ks < D_IN / 32; ++ks) {
        short8 af = *(const short8*)&As[(rsub * 16 + m) * KP + ks * 32 + quad * 8];
#pragma unroll
        for (int ct = 0; ct < 4; ++ct) {
            int ct4 = cth * 4 + ct;
            short8 bf = *(const short8*)&Wsw[(size_t)((ct4 * (D_IN / 32) + ks) * 64 + lane) * 8];
            acc[ct] = __builtin_amdgcn_mfma_f32_16x16x32_bf16(af, bf, acc[ct], 0, 0, 0);
        }
    }

    int rbase = row0 + rsub * 16 + quad * 4;
#pragma unroll
    for (int ct = 0; ct < 4; ++ct) {
        int col = (cth * 4 + ct) * 16 + m;
#pragma unroll
        for (int reg = 0; reg < 4; ++reg) {
            int r = rbase + reg;
            if (r < N_NODES) H[(size_t)r * D_HID + col] = f2bf(acc[ct][reg]);
        }
    }
}

// ---------------- D2: bucket scan (98) || GEMM half-A (391) ----------------
// Scan block b: exclusive scan of rowcnt over nodes [b*512, b*512+512);
// rowptr/gcur = b*BCAPS + excl; dinv = rsqrt(cnt+1). Fixed-capacity bucket
// regions make the scan block-local (no global prefix sum).
__global__ __launch_bounds__(512) void sg_k(const int* __restrict__ rowcnt,
                                            int* __restrict__ rowptr,
                                            int* __restrict__ gcur,
                                            float* __restrict__ dinv,
                                            const floatx4* __restrict__ X4,
                                            const unsigned short* __restrict__ Wsw,
                                            unsigned short* __restrict__ H) {
    extern __shared__ char dynsm[];
    int tid = threadIdx.x;
    if (blockIdx.x < NBUKS) {
        int* s = (int*)dynsm;                     // 512 ints
        int b = blockIdx.x;
        int node = (b << 9) + tid;
        bool valid = node < N_NODES;
        int cnt = valid ? rowcnt[node] : 0;
        s[tid] = cnt;
        __syncthreads();
        for (int off = 1; off < 512; off <<= 1) {
            int t = (tid >= off) ? s[tid - off] : 0;
            __syncthreads();
            s[tid] += t;
            __syncthreads();
        }
        if (valid) {
            int rp = b * BCAPS + (s[tid] - cnt);
            rowptr[node] = rp;
            gcur[node]   = rp;
            dinv[node]   = rsqrtf((float)(cnt + 1));   // +1 self-loop
        }
    } else {
        gemm_path(dynsm, (blockIdx.x - NBUKS) * 64, X4, Wsw, H);
    }
}

// ---------------- D3: edge scatter (196) || GEMM half-B (391) ----------------
// Scatter: srcs[atomicAdd(&gcur[d],1)] = src. Counts are exact (same edges as
// the D1 count), so positions exactly fill [rowptr, rowptr+cnt) — no overflow.
__global__ __launch_bounds__(512) void cg_k(const int* __restrict__ rows,
                                            const int* __restrict__ cols,
                                            int* __restrict__ gcur,
                                            unsigned short* __restrict__ srcs,
                                            const floatx4* __restrict__ X4,
                                            const unsigned short* __restrict__ Wsw,
                                            unsigned short* __restrict__ H) {
    extern __shared__ char dynsm[];
    int tid = threadIdx.x;
    if (blockIdx.x < NDEGB) {
        int e0 = blockIdx.x * 4096;
#pragma unroll
        for (int j = 0; j < 8; ++j) {
            int e = e0 + j * 512 + tid;
            if (e < N_EDGES) {
                int s = rows[e], d = cols[e];
                int p = atomicAdd(&gcur[d], 1);
                srcs[p] = (unsigned short)s;
            }
        }
    } else {
        gemm_path(dynsm, (NGEMB_A + blockIdx.x - NDEGB) * 64, X4, Wsw, H);
    }
}

// x8-deep WEIGHTED gather: acc += dinv[s] * h1raw[s]; 8 loads in flight.
#define WGATHER(SP)                                                            \
    {                                                                          \
        const auto* sp_ = (SP);                                                \
        int i = 0;                                                             \
        for (; i + 8 <= cnt; i += 8) {                                         \
            int s0 = sp_[i],     s1 = sp_[i + 1], s2 = sp_[i + 2], s3 = sp_[i + 3]; \
            int s4 = sp_[i + 4], s5 = sp_[i + 5], s6 = sp_[i + 6], s7 = sp_[i + 7]; \
            float w0 = dinv[s0], w1 = dinv[s1], w2 = dinv[s2], w3 = dinv[s3];  \
            float w4 = dinv[s4], w5 = dinv[s5], w6 = dinv[s6], w7 = dinv[s7];  \
            ushort8v v0 = hs[(size_t)s0 * 16 + d8], v1 = hs[(size_t)s1 * 16 + d8]; \
            ushort8v v2 = hs[(size_t)s2 * 16 + d8], v3 = hs[(size_t)s3 * 16 + d8]; \
            ushort8v v4 = hs[(size_t)s4 * 16 + d8], v5 = hs[(size_t)s5 * 16 + d8]; \
            ushort8v v6 = hs[(size_t)s6 * 16 + d8], v7 = hs[(size_t)s7 * 16 + d8]; \
            a0 += bf2f8(v0) * w0; a1 += bf2f8(v1) * w1;                        \
            a2 += bf2f8(v2) * w2; a3 += bf2f8(v3) * w3;                        \
            a0 += bf2f8(v4) * w4; a1 += bf2f8(v5) * w5;                        \
            a2 += bf2f8(v6) * w6; a3 += bf2f8(v7) * w7;                        \
        }                                                                      \
        if (i + 4 <= cnt) {                                                    \
            int s0 = sp_[i], s1 = sp_[i + 1], s2 = sp_[i + 2], s3 = sp_[i + 3]; \
            a0 += bf2f8(hs[(size_t)s0 * 16 + d8]) * dinv[s0];                  \
            a1 += bf2f8(hs[(size_t)s1 * 16 + d8]) * dinv[s1];                  \
            a2 += bf2f8(hs[(size_t)s2 * 16 + d8]) * dinv[s2];                  \
            a3 += bf2f8(hs[(size_t)s3 * 16 + d8]) * dinv[s3];                  \
            i += 4;                                                            \
        }                                                                      \
        for (; i < cnt; ++i) {                                                 \
            int s = sp_[i];                                                    \
            a0 += bf2f8(hs[(size_t)s * 16 + d8]) * dinv[s];                    \
        }                                                                      \
    }

// ---------------- D4: fused gather1 + relu + FC-folded projection ----------------
// z[v] = dinv[v] * ( relu(dinv[v]*Σ dinv[s]*h1raw[s] + b1) @ w2fc )  — scalar per node.
// Block = 256 (4 waves), 16 nodes/block, 16 lanes/node; CSR window in LDS.
// Windows are contiguous: 16-node groups align within 512-node bucket regions.
__global__ __launch_bounds__(256) void g1z_k(const ushort8v* __restrict__ hs,
                                             const int* __restrict__ rowptr,
                                             const int* __restrict__ rowcnt,
                                             const unsigned short* __restrict__ srcs,
                                             const float* __restrict__ dinv,
                                             const float4* __restrict__ b1_4,
                                             const float4* __restrict__ w2fc4,
                                             float* __restrict__ z) {
    __shared__ unsigned short sidx[1024];   // expected ~256 (Poisson), huge margin
    __shared__ int sb2[2];
    int tid = threadIdx.x;
    int nodeb = blockIdx.x * 16;    // 50000 = 3125*16 exactly
    int ln = tid >> 4;              // local node 0..15
    int d8 = tid & 15;
    int node = nodeb + ln;
    int beg = rowptr[node];
    int cnt = rowcnt[node];
    if (tid == 0)   sb2[0] = beg;         // ln==0
    if (tid == 240) sb2[1] = beg + cnt;   // ln==15
    ushort8v selfv = hs[(size_t)node * 16 + d8];   // hoisted self-loop row
    float di = dinv[node];
    __syncthreads();
    int base = sb2[0], total = sb2[1] - base;
    for (int t = tid; t < total && t < 1024; t += 256) sidx[t] = srcs[base + t];
    __syncthreads();

    floatx8 a0 = {0,0,0,0,0,0,0,0}, a1 = a0, a2 = a0, a3 = a0;
    if (total <= 1024) {
        WGATHER(sidx + (beg - base))
    } else {
        WGATHER(srcs + beg)
    }
    floatx8 acc = a0 + a1 + a2 + a3 + bf2f8(selfv) * di;
    float4 bA = b1_4[d8 * 2],  bB = b1_4[d8 * 2 + 1];
    float4 wA = w2fc4[d8 * 2], wB = w2fc4[d8 * 2 + 1];
    float s = fmaxf(di * acc[0] + bA.x, 0.0f) * wA.x
            + fmaxf(di * acc[1] + bA.y, 0.0f) * wA.y
            + fmaxf(di * acc[2] + bA.z, 0.0f) * wA.z
            + fmaxf(di * acc[3] + bA.w, 0.0f) * wA.w
            + fmaxf(di * acc[4] + bB.x, 0.0f) * wB.x
            + fmaxf(di * acc[5] + bB.y, 0.0f) * wB.y
            + fmaxf(di * acc[6] + bB.z, 0.0f) * wB.z
            + fmaxf(di * acc[7] + bB.w, 0.0f) * wB.w;
#pragma unroll
    for (int off = 8; off; off >>= 1) s += __shfl_xor(s, off, 16);
    if (d8 == 0) z[node] = di * s;
}

// ---------------- D5: scalar propagation + sigmoid ----------------
// out[v] = sigmoid( dinv[v] * (Σ z[nbr] + z[v]) + b2fc + bfc ); z is 200 KB L2-resident.
__global__ __launch_bounds__(256) void gatherz_k(const float* __restrict__ z,
                                                 const int* __restrict__ rowptr,
                                                 const int* __restrict__ rowcnt,
                                                 const unsigned short* __restrict__ srcs,
                                                 const float* __restrict__ dinv,
                                                 const float* __restrict__ b2fc,
                                                 const float* __restrict__ bfc,
                                                 float* __restrict__ out) {
    int v = blockIdx.x * 256 + threadIdx.x;
    if (v >= N_NODES) return;
    int beg = rowptr[v], cnt = rowcnt[v];
    float s0 = z[v], s1 = 0.0f, s2 = 0.0f, s3 = 0.0f;
    int i = beg, end = beg + cnt;
    for (; i + 4 <= end; i += 4) {
        s0 += z[srcs[i]];
        s1 += z[srcs[i + 1]];
        s2 += z[srcs[i + 2]];
        s3 += z[srcs[i + 3]];
    }
    for (; i < end; ++i) s0 += z[srcs[i]];
    float p = dinv[v] * (s0 + s1 + s2 + s3) + b2fc[0] + bfc[0];
    out[v] = 1.0f / (1.0f + expf(-p));
}

extern "C" void kernel_launch(void* const* d_in, const int* in_sizes, int n_in,
                              void* d_out, int out_size, void* d_ws, size_t ws_size,
                              hipStream_t stream) {
    const float* x   = (const float*)d_in[0];
    const int*   ei  = (const int*)d_in[1];     // [2, E] int32
    const float* W1  = (const float*)d_in[2];
    const float* b1  = (const float*)d_in[3];
    const float* W2  = (const float*)d_in[4];
    const float* b2  = (const float*)d_in[5];
    const float* Wfc = (const float*)d_in[6];
    const float* bfc = (const float*)d_in[7];
    float* out = (float*)d_out;

    const int* rows = ei;             // sources
    const int* cols = ei + N_EDGES;   // targets

    // workspace layout (16B alignment kept for vector types)
    float* ws     = (float*)d_ws;
    float* dinv   = ws;                                   // 50048 f
    int*   rowptr = (int*)(ws + 50048);                   // 50048
    int*   rowcnt = rowptr + 50048;                       // 50048
    int*   gcur   = rowcnt + 50048;                       // 50048
    unsigned short* srcs = (unsigned short*)(gcur + 50048);       // NBUKS*BCAPS u16 (3.2MB)
    unsigned short* h1 = srcs + (size_t)NBUKS * BCAPS;            // 6.4M u16 (12.8MB)
    unsigned short* Wsw1 = h1 + (size_t)N_NODES * D_HID;          // 32768 us
    float* z    = (float*)(Wsw1 + (size_t)D_IN * D_HID);          // 50000 f
    float* w2fc = z + 50000;                                      // 128 f
    float* b2fc = w2fc + 128;                                     // 1 f

    // ---- D0: zero in-degree counters (200 KB) ----
    hipMemsetAsync(rowcnt, 0, 50048 * sizeof(int), stream);

    // ---- D1: weight swizzle + FC fold (9) || in-degree count (196) ----
    pd_k<<<NPREPB + NDEGB, 512, 0, stream>>>(W1, W2, b2, Wfc, Wsw1, w2fc, b2fc,
                                             cols, rowcnt);

    // ---- D2: bucket scan -> rowptr/gcur/dinv (98) || GEMM rows [0,25024) (391) ----
    sg_k<<<NBUKS + NGEMB_A, 512, DYN_LDS, stream>>>(rowcnt, rowptr, gcur, dinv,
                                                    (const floatx4*)x, Wsw1, h1);

    // ---- D3: edge scatter -> srcs (196) || GEMM rows [25024,50048) (391) ----
    cg_k<<<NDEGB + NGEMB_B, 512, DYN_LDS, stream>>>(rows, cols, gcur, srcs,
                                                    (const floatx4*)x, Wsw1, h1);

    // ---- D4: fused gather1 (dinv-weighted) + relu + (W2 @ Wfc) projection -> z ----
    g1z_k<<<N_NODES / 16, 256, 0, stream>>>((const ushort8v*)h1, rowptr, rowcnt, srcs, dinv,
                                            (const float4*)b1, (const float4*)w2fc, z);

    // ---- D5: scalar propagation + sigmoid ----
    gatherz_k<<<(N_NODES + 255) / 256, 256, 0, stream>>>(z, rowptr, rowcnt, srcs, dinv,
                                                         b2fc, bfc, out);
}

// Round 13
// 167.930 us; speedup vs baseline: 1.3031x; 1.3031x over previous
//
#include <hip/hip_runtime.h>
#include <hip/hip_bf16.h>
#include <cmath>

#define N_NODES 50000
#define N_EDGES 800000
#define D_IN 256
#define D_HID 128
#define D_ENC 64
#define NBUK 128         // dest buckets (pow2 for scan), bucket = d >> 9; 98 used
#define BSH 9
#define BMSK 511
#define NCSRB 98         // used buckets = ceil(N_NODES/512)
#define NPARTB 196       // ceil(N_EDGES/4096) part blocks
#define NPREPB 9         // prep blocks (4608 threads cover swizzle+fold)
#define CHUNK 128        // records per (bucket, part-block) chunk; mean 42, +13 sigma
#define BCAPB (NPARTB * CHUNK)   // 25088 u32 per bucket in brecs
#define SCAP 16384       // u16 srcs slots per bucket (max total ~8650)
#define NGEMB 782        // ceil(50048/64) GEMM tile-blocks
#define LDS_PP 17408     // part: recs 16K + h/ex 1K
#define LDS_GC 37376     // csr: 4K(s,cur) + 32K(sl) + 512(scnt); gemm: 33792

typedef short short8 __attribute__((ext_vector_type(8)));
typedef float floatx4 __attribute__((ext_vector_type(4)));
typedef float floatx8 __attribute__((ext_vector_type(8)));
typedef unsigned short ushort8v __attribute__((ext_vector_type(8)));

static __device__ __forceinline__ unsigned short f2bf(float f) {
    unsigned int u = __float_as_uint(f);
    unsigned int r = (u + 0x7FFFu + ((u >> 16) & 1u)) >> 16;   // RNE
    return (unsigned short)r;
}
static __device__ __forceinline__ float bf2f(unsigned short u) {
    return __uint_as_float(((unsigned int)u) << 16);
}
static __device__ __forceinline__ floatx8 bf2f8(ushort8v u) {
    floatx8 f;
#pragma unroll
    for (int j = 0; j < 8; ++j) f[j] = bf2f(u[j]);
    return f;
}

// ---------------- W pre-swizzle into B-fragment layout (bf16) ----------------
static __device__ __forceinline__ void wswz(const float* __restrict__ W,
                                            unsigned short* __restrict__ Wsw,
                                            int t, int K, int N) {
    int KS = K / 32;
    int lane = t & 63;
    int ks   = (t >> 6) % KS;
    int ct   = (t >> 6) / KS;
    int m = lane & 15, quad = lane >> 4;
    int kbase = ks * 32 + quad * 8;
    int col   = ct * 16 + m;
#pragma unroll
    for (int j = 0; j < 8; ++j)
        Wsw[t * 8 + j] = f2bf(W[(size_t)(kbase + j) * N + col]);
}

// ---------------- device: radix partition, DETERMINISTIC chunk placement ----------------
// Block pb sorts its 4096 edges by bucket in LDS, then flushes bucket b's records
// to the fixed chunk brecs[b*BCAPB + pb*CHUNK] with count cnts[b*NPARTB+pb].
// No global atomics, no pre-zeroed counters -> can co-dispatch with prep.
static __device__ void part_path(char* dynsm, int pb,
                                 const int* rows, const int* cols,
                                 unsigned int* brecs, unsigned short* cnts) {
    unsigned int* recs = (unsigned int*)dynsm;        // 4096 u32 (16 KB)
    int* h  = (int*)(dynsm + 16384);                  // NBUK
    int* ex = h + NBUK;                               // NBUK
    int tid = threadIdx.x;
    if (tid < NBUK) h[tid] = 0;
    __syncthreads();
    int e0 = pb * 4096;
    unsigned int myrec[8];
    int myb[8];
#pragma unroll
    for (int j = 0; j < 8; ++j) {
        int e = e0 + j * 512 + tid;
        if (e < N_EDGES) {
            int s = rows[e], d = cols[e];
            myrec[j] = ((unsigned int)s << 16) | (unsigned int)d;
            myb[j] = d >> BSH;
            atomicAdd(&h[myb[j]], 1);
        } else myb[j] = -1;
    }
    __syncthreads();
    if (tid < NBUK) ex[tid] = h[tid];
    __syncthreads();
    for (int off = 1; off < NBUK; off <<= 1) {
        int v = 0;
        if (tid < NBUK && tid >= off) v = ex[tid - off];
        __syncthreads();
        if (tid < NBUK) ex[tid] += v;
        __syncthreads();
    }
    if (tid < NBUK) { ex[tid] -= h[tid]; h[tid] = 0; }
    __syncthreads();
#pragma unroll
    for (int j = 0; j < 8; ++j) {
        if (myb[j] >= 0) {
            int p = ex[myb[j]] + atomicAdd(&h[myb[j]], 1);
            recs[p] = myrec[j];
        }
    }
    __syncthreads();
    int w = tid >> 6, lane = tid & 63;
    for (int b = w; b < NBUK; b += 8) {
        int start = ex[b], c = h[b];
        int cw = c < CHUNK ? c : CHUNK;               // clamp (13-sigma, never hit)
        if (lane == 0) cnts[b * NPARTB + pb] = (unsigned short)cw;
        if (b < NCSRB) {                              // buckets >= 98 are always empty
            unsigned int gb = (unsigned int)b * BCAPB + pb * CHUNK;
            for (int i = lane; i < cw; i += 64)
                brecs[gb + i] = recs[start + i];
        }
    }
}

// ---------------- D1: prep (9) || radix partition (196) ----------------
__global__ __launch_bounds__(512) void pp_k(const float* __restrict__ W1,
                                            const float* __restrict__ W2,
                                            const float* __restrict__ b2,
                                            const float* __restrict__ Wfc,
                                            unsigned short* __restrict__ Wsw1,
                                            float* __restrict__ w2fc,
                                            float* __restrict__ b2fc,
                                            const int* __restrict__ rows,
                                            const int* __restrict__ cols,
                                            unsigned int* __restrict__ brecs,
                                            unsigned short* __restrict__ cnts) {
    extern __shared__ char dynsm[];
    int tid = threadIdx.x;
    if (blockIdx.x < NPREPB) {
        int t = blockIdx.x * 512 + tid;               // 0..4607
        if (t < 4096) wswz(W1, Wsw1, t, D_IN, D_HID);
        else if (t < 4224) {                          // w2fc[c] = sum_j W2[c][j]*Wfc[j]
            int c = t - 4096;
            float s = 0.0f;
#pragma unroll 8
            for (int j = 0; j < D_ENC; ++j) s += W2[c * D_ENC + j] * Wfc[j];
            w2fc[c] = s;
        } else if (t == 4224) {                       // b2fc = b2 @ Wfc
            float s = 0.0f;
            for (int j = 0; j < D_ENC; ++j) s += b2[j] * Wfc[j];
            b2fc[0] = s;
        }
    } else {
        part_path(dynsm, blockIdx.x - NPREPB, rows, cols, brecs, cnts);
    }
}

// ---------------- device: per-bucket CSR from chunked brecs (512 thr) ----------------
static __device__ void csr_path(char* dynsm, int b,
                                const unsigned int* brecs, const unsigned short* cnts,
                                int* rowptr, int* rowcnt,
                                unsigned short* srcs, float* dinv) {
    int* s   = (int*)dynsm;                           // 512 ints
    int* cur = (int*)(dynsm + 2048);                  // 512 ints
    unsigned short* sl = (unsigned short*)(dynsm + 4096);      // SCAP u16 (32 KB)
    unsigned short* scnt = (unsigned short*)(dynsm + 36864);   // NPARTB u16
    int tid = threadIdx.x;
    if (tid < NPARTB) scnt[tid] = cnts[b * NPARTB + tid];
    s[tid] = 0;
    __syncthreads();
    const unsigned int* bb = brecs + (size_t)b * BCAPB;
    // pass A: histogram destinations (padded-stride walk over 196 chunks)
    for (int idx = tid; idx < (NPARTB << 7); idx += 512) {
        int pb = idx >> 7, i = idx & (CHUNK - 1);
        if (i < (int)scnt[pb]) atomicAdd(&s[bb[idx] & BMSK], 1);
    }
    __syncthreads();
    int v = s[tid];
    for (int off = 1; off < 512; off <<= 1) {
        int t = (tid >= off) ? s[tid - off] : 0;
        __syncthreads();
        s[tid] += t;
        __syncthreads();
    }
    int excl = s[tid] - v;
    cur[tid] = excl;
    int total = s[511];
    int node = (b << BSH) + tid;
    if (node < N_NODES) {
        rowptr[node] = b * SCAP + excl;
        rowcnt[node] = v;
        dinv[node] = rsqrtf((float)(v + 1));          // +1 self-loop
    }
    __syncthreads();
    // pass B: scatter sources into LDS at sorted positions
    for (int idx = tid; idx < (NPARTB << 7); idx += 512) {
        int pb = idx >> 7, i = idx & (CHUNK - 1);
        if (i < (int)scnt[pb]) {
            unsigned int rec = bb[idx];
            int p = atomicAdd(&cur[rec & BMSK], 1);
            sl[p] = (unsigned short)(rec >> 16);
        }
    }
    __syncthreads();
    // coalesced u32 flush (total ~8.2K << SCAP; pad slot stays in-bucket)
    int nw = (total + 1) >> 1;
    unsigned int* s32 = (unsigned int*)(srcs + b * SCAP);
    const unsigned int* l32 = (const unsigned int*)sl;
    for (int t = tid; t < nw; t += 512) s32[t] = l32[t];
}

// ---------------- device: one 64-row MFMA GEMM tile (512 thr) ----------------
// H[r,:] = bf16(X[r,:] @ W1)   (dinv weighting applied in the gather)
static __device__ void gemm_path(char* dynsm, int row0,
                                 const floatx4* X4, const unsigned short* Wsw,
                                 unsigned short* H) {
    constexpr int KP = D_IN + 8;   // 264
    unsigned short* As = (unsigned short*)dynsm;      // 64*KP u16 (33 KB)
    int tid = threadIdx.x;
    for (int idx = tid; idx < 64 * 64; idx += 512) {
        int r = idx >> 6, c4 = idx & 63;
        int gr = row0 + r;
        floatx4 v = (gr < N_NODES) ? X4[(size_t)gr * 64 + c4] : (floatx4){0, 0, 0, 0};
        __hip_bfloat162 p0 = __float22bfloat162_rn(float2{v[0], v[1]});   // packed RNE cvt
        __hip_bfloat162 p1 = __float22bfloat162_rn(float2{v[2], v[3]});
        uint2 u; u.x = *(unsigned int*)&p0; u.y = *(unsigned int*)&p1;
        *(uint2*)&As[r * KP + c4 * 4] = u;
    }
    __syncthreads();

    int w    = tid >> 6;
    int lane = tid & 63;
    int m    = lane & 15;
    int quad = lane >> 4;
    int rsub = w & 3;
    int cth  = w >> 2;              // 0/1: which 4 col-tiles

    floatx4 acc[4];
#pragma unroll
    for (int ct = 0; ct < 4; ++ct)
#pragma unroll
        for (int i = 0; i < 4; ++i) acc[ct][i] = 0.0f;

#pragma unroll
    for (int ks = 0; ks < D_IN / 32; ++ks) {
        short8 af = *(const short8*)&As[(rsub * 16 + m) * KP + ks * 32 + quad * 8];
#pragma unroll
        for (int ct = 0; ct < 4; ++ct) {
            int ct4 = cth * 4 + ct;
            short8 bf = *(const short8*)&Wsw[(size_t)((ct4 * (D_IN / 32) + ks) * 64 + lane) * 8];
            acc[ct] = __builtin_amdgcn_mfma_f32_16x16x32_bf16(af, bf, acc[ct], 0, 0, 0);
        }
    }

    int rbase = row0 + rsub * 16 + quad * 4;
#pragma unroll
    for (int ct = 0; ct < 4; ++ct) {
        int col = (cth * 4 + ct) * 16 + m;
#pragma unroll
        for (int reg = 0; reg < 4; ++reg) {
            int r = rbase + reg;
            if (r < N_NODES) H[(size_t)r * D_HID + col] = f2bf(acc[ct][reg]);
        }
    }
}

// ---------------- D2: bucket-CSR (98) || layer-1 GEMM (782) — csr hides under gemm ----------------
__global__ __launch_bounds__(512) void gc_k(const unsigned int* __restrict__ brecs,
                                            const unsigned short* __restrict__ cnts,
                                            int* __restrict__ rowptr,
                                            int* __restrict__ rowcnt,
                                            unsigned short* __restrict__ srcs,
                                            float* __restrict__ dinv,
                                            const floatx4* __restrict__ X4,
                                            const unsigned short* __restrict__ Wsw,
                                            unsigned short* __restrict__ H) {
    extern __shared__ char dynsm[];
    if (blockIdx.x < NCSRB)
        csr_path(dynsm, blockIdx.x, brecs, cnts, rowptr, rowcnt, srcs, dinv);
    else
        gemm_path(dynsm, (blockIdx.x - NCSRB) * 64, X4, Wsw, H);
}

// x8-deep WEIGHTED gather: acc += dinv[s] * h1raw[s]; 8 loads in flight.
#define WGATHER(SP)                                                            \
    {                                                                          \
        const auto* sp_ = (SP);                                                \
        int i = 0;                                                             \
        for (; i + 8 <= cnt; i += 8) {                                         \
            int s0 = sp_[i],     s1 = sp_[i + 1], s2 = sp_[i + 2], s3 = sp_[i + 3]; \
            int s4 = sp_[i + 4], s5 = sp_[i + 5], s6 = sp_[i + 6], s7 = sp_[i + 7]; \
            float w0 = dinv[s0], w1 = dinv[s1], w2 = dinv[s2], w3 = dinv[s3];  \
            float w4 = dinv[s4], w5 = dinv[s5], w6 = dinv[s6], w7 = dinv[s7];  \
            ushort8v v0 = hs[(size_t)s0 * 16 + d8], v1 = hs[(size_t)s1 * 16 + d8]; \
            ushort8v v2 = hs[(size_t)s2 * 16 + d8], v3 = hs[(size_t)s3 * 16 + d8]; \
            ushort8v v4 = hs[(size_t)s4 * 16 + d8], v5 = hs[(size_t)s5 * 16 + d8]; \
            ushort8v v6 = hs[(size_t)s6 * 16 + d8], v7 = hs[(size_t)s7 * 16 + d8]; \
            a0 += bf2f8(v0) * w0; a1 += bf2f8(v1) * w1;                        \
            a2 += bf2f8(v2) * w2; a3 += bf2f8(v3) * w3;                        \
            a0 += bf2f8(v4) * w4; a1 += bf2f8(v5) * w5;                        \
            a2 += bf2f8(v6) * w6; a3 += bf2f8(v7) * w7;                        \
        }                                                                      \
        if (i + 4 <= cnt) {                                                    \
            int s0 = sp_[i], s1 = sp_[i + 1], s2 = sp_[i + 2], s3 = sp_[i + 3]; \
            a0 += bf2f8(hs[(size_t)s0 * 16 + d8]) * dinv[s0];                  \
            a1 += bf2f8(hs[(size_t)s1 * 16 + d8]) * dinv[s1];                  \
            a2 += bf2f8(hs[(size_t)s2 * 16 + d8]) * dinv[s2];                  \
            a3 += bf2f8(hs[(size_t)s3 * 16 + d8]) * dinv[s3];                  \
            i += 4;                                                            \
        }                                                                      \
        for (; i < cnt; ++i) {                                                 \
            int s = sp_[i];                                                    \
            a0 += bf2f8(hs[(size_t)s * 16 + d8]) * dinv[s];                    \
        }                                                                      \
    }

// ---------------- D3: fused gather1 + relu + FC-folded projection ----------------
// z[v] = dinv[v] * ( relu(dinv[v]*Σ dinv[s]*h1raw[s] + b1) @ w2fc )  — scalar per node.
// Block = 256 (4 waves), 16 nodes/block, 16 lanes/node; CSR window in LDS.
// Windows contiguous: 16-node groups lie within one 512-node bucket (512 % 16 == 0).
__global__ __launch_bounds__(256) void g1z_k(const ushort8v* __restrict__ hs,
                                             const int* __restrict__ rowptr,
                                             const int* __restrict__ rowcnt,
                                             const unsigned short* __restrict__ srcs,
                                             const float* __restrict__ dinv,
                                             const float4* __restrict__ b1_4,
                                             const float4* __restrict__ w2fc4,
                                             float* __restrict__ z) {
    __shared__ unsigned short sidx[1024];   // expected ~256 (Poisson), huge margin
    __shared__ int sb2[2];
    int tid = threadIdx.x;
    int nodeb = blockIdx.x * 16;    // 50000 = 3125*16 exactly
    int ln = tid >> 4;              // local node 0..15
    int d8 = tid & 15;
    int node = nodeb + ln;
    int beg = rowptr[node];
    int cnt = rowcnt[node];
    if (tid == 0)   sb2[0] = beg;         // ln==0
    if (tid == 240) sb2[1] = beg + cnt;   // ln==15
    ushort8v selfv = hs[(size_t)node * 16 + d8];   // hoisted self-loop row
    float di = dinv[node];
    __syncthreads();
    int base = sb2[0], total = sb2[1] - base;
    for (int t = tid; t < total && t < 1024; t += 256) sidx[t] = srcs[base + t];
    __syncthreads();

    floatx8 a0 = {0,0,0,0,0,0,0,0}, a1 = a0, a2 = a0, a3 = a0;
    if (total <= 1024) {
        WGATHER(sidx + (beg - base))
    } else {
        WGATHER(srcs + beg)
    }
    floatx8 acc = a0 + a1 + a2 + a3 + bf2f8(selfv) * di;
    float4 bA = b1_4[d8 * 2],  bB = b1_4[d8 * 2 + 1];
    float4 wA = w2fc4[d8 * 2], wB = w2fc4[d8 * 2 + 1];
    float s = fmaxf(di * acc[0] + bA.x, 0.0f) * wA.x
            + fmaxf(di * acc[1] + bA.y, 0.0f) * wA.y
            + fmaxf(di * acc[2] + bA.z, 0.0f) * wA.z
            + fmaxf(di * acc[3] + bA.w, 0.0f) * wA.w
            + fmaxf(di * acc[4] + bB.x, 0.0f) * wB.x
            + fmaxf(di * acc[5] + bB.y, 0.0f) * wB.y
            + fmaxf(di * acc[6] + bB.z, 0.0f) * wB.z
            + fmaxf(di * acc[7] + bB.w, 0.0f) * wB.w;
#pragma unroll
    for (int off = 8; off; off >>= 1) s += __shfl_xor(s, off, 16);
    if (d8 == 0) z[node] = di * s;
}

// ---------------- D4: scalar propagation + sigmoid ----------------
// out[v] = sigmoid( dinv[v] * (Σ z[nbr] + z[v]) + b2fc + bfc ); z is 200 KB L2-resident.
__global__ __launch_bounds__(256) void gatherz_k(const float* __restrict__ z,
                                                 const int* __restrict__ rowptr,
                                                 const int* __restrict__ rowcnt,
                                                 const unsigned short* __restrict__ srcs,
                                                 const float* __restrict__ dinv,
                                                 const float* __restrict__ b2fc,
                                                 const float* __restrict__ bfc,
                                                 float* __restrict__ out) {
    int v = blockIdx.x * 256 + threadIdx.x;
    if (v >= N_NODES) return;
    int beg = rowptr[v], cnt = rowcnt[v];
    float s0 = z[v], s1 = 0.0f, s2 = 0.0f, s3 = 0.0f;
    int i = beg, end = beg + cnt;
    for (; i + 4 <= end; i += 4) {
        s0 += z[srcs[i]];
        s1 += z[srcs[i + 1]];
        s2 += z[srcs[i + 2]];
        s3 += z[srcs[i + 3]];
    }
    for (; i < end; ++i) s0 += z[srcs[i]];
    float p = dinv[v] * (s0 + s1 + s2 + s3) + b2fc[0] + bfc[0];
    out[v] = 1.0f / (1.0f + expf(-p));
}

extern "C" void kernel_launch(void* const* d_in, const int* in_sizes, int n_in,
                              void* d_out, int out_size, void* d_ws, size_t ws_size,
                              hipStream_t stream) {
    const float* x   = (const float*)d_in[0];
    const int*   ei  = (const int*)d_in[1];     // [2, E] int32
    const float* W1  = (const float*)d_in[2];
    const float* b1  = (const float*)d_in[3];
    const float* W2  = (const float*)d_in[4];
    const float* b2  = (const float*)d_in[5];
    const float* Wfc = (const float*)d_in[6];
    const float* bfc = (const float*)d_in[7];
    float* out = (float*)d_out;

    const int* rows = ei;             // sources
    const int* cols = ei + N_EDGES;   // targets

    // workspace layout (all segments multiples of 16 B)
    float* ws     = (float*)d_ws;
    float* dinv   = ws;                                   // 50048 f
    int*   rowptr = (int*)(ws + 50048);                   // 50048
    int*   rowcnt = rowptr + 50048;                       // 50048
    unsigned short* cnts = (unsigned short*)(rowcnt + 50048);      // 128*196 u16 (50 KB)
    unsigned int*   brecs = (unsigned int*)(cnts + NBUK * NPARTB); // 98*25088 u32 (9.8 MB)
    unsigned short* srcs = (unsigned short*)(brecs + (size_t)NCSRB * BCAPB);  // 98*16384 u16 (3.2 MB)
    unsigned short* h1 = srcs + (size_t)NCSRB * SCAP;              // 6.4M u16 (12.8 MB)
    unsigned short* Wsw1 = h1 + (size_t)N_NODES * D_HID;           // 32768 u16
    float* z    = (float*)(Wsw1 + (size_t)D_IN * D_HID);           // 50000 f
    float* w2fc = z + 50000;                                       // 128 f
    float* b2fc = w2fc + 128;                                      // 1 f

    // ---- D1: weight swizzle + FC fold (9) || radix partition, chunked (196) ----
    pp_k<<<NPREPB + NPARTB, 512, LDS_PP, stream>>>(W1, W2, b2, Wfc, Wsw1, w2fc, b2fc,
                                                   rows, cols, brecs, cnts);

    // ---- D2: bucket-CSR from chunks (98) || layer-1 GEMM (782) ----
    gc_k<<<NCSRB + NGEMB, 512, LDS_GC, stream>>>(brecs, cnts, rowptr, rowcnt, srcs, dinv,
                                                 (const floatx4*)x, Wsw1, h1);

    // ---- D3: fused gather1 (dinv-weighted) + relu + (W2 @ Wfc) projection -> z ----
    g1z_k<<<N_NODES / 16, 256, 0, stream>>>((const ushort8v*)h1, rowptr, rowcnt, srcs, dinv,
                                            (const float4*)b1, (const float4*)w2fc, z);

    // ---- D4: scalar propagation + sigmoid ----
    gatherz_k<<<(N_NODES + 255) / 256, 256, 0, stream>>>(z, rowptr, rowcnt, srcs, dinv,
                                                         b2fc, bfc, out);
}